// Round 4
// baseline (400.887 us; speedup 1.0000x reference)
//
#include <hip/hip_runtime.h>
#include <hip/hip_bf16.h>
#include <math.h>

#define DEV __device__ __forceinline__

typedef __attribute__((ext_vector_type(8))) short bf16x8;   // 8 bf16 in 4 VGPRs
typedef __attribute__((ext_vector_type(4))) float f32x4;
typedef __attribute__((ext_vector_type(4))) unsigned int u32x4;
typedef __attribute__((ext_vector_type(2))) unsigned int u32x2;

DEV float b2f(unsigned int u) { return __uint_as_float(u << 16); }
DEV unsigned short f2b(float f) {            // round-to-nearest-even bf16
    unsigned int x = __float_as_uint(f);
    unsigned int r = x + 0x7fffu + ((x >> 16) & 1u);
    return (unsigned short)(r >> 16);
}
DEV unsigned int pack2(float a, float b) {
    return (unsigned int)f2b(a) | ((unsigned int)f2b(b) << 16);
}
DEV float gelu_exact(float g) {
    return 0.5f * g * (1.f + erff(g * 0.70710678118654752f));
}

// ---------------- workspace layout (bytes) ----------------
constexpr size_t WP1  = 0;                 // conv1 packed w
constexpr size_t WP2  = WP1  + 1179648;
constexpr size_t BPQ  = WP2  + 1179648;    // wq packed
constexpr size_t BPO  = BPQ  + 32768;      // wo packed
constexpr size_t BP1  = BPO  + 32768;      // w1 packed
constexpr size_t BP2  = BP1  + 262144;     // w2 packed
constexpr size_t XTP  = BP2  + 131072;     // x channel-last padded [32][324][256] bf16
constexpr size_t O1P  = XTP  + 5308416;    // conv1 out, padded layout, bf16
constexpr size_t TBUF = O1P  + 5308416;    // t [8192][256] f32
constexpr size_t QB   = TBUF + 8388608;    // q [8192][64] bf16
constexpr size_t E0P  = QB   + 1048576;    // e0 packed B-frags, 16 KB
constexpr size_t DIST = E0P  + 16384;      // [32][100000] f32
constexpr size_t CANDV= DIST + 12800000;   // [32][2048] f32
constexpr size_t CANDI= CANDV+ 262144;     // [32][2048] i32
constexpr size_t IDXB = CANDI+ 262144;     // (unused)
constexpr size_t KBF  = IDXB + 4096;       // k [32][32][64] f32
constexpr size_t VBF  = KBF  + 262144;     // v
constexpr size_t OBF  = VBF  + 262144;     // (unused now)

// ================ setup: weight repacks + x transpose/pad (balanced) ================
// blocks: [0,576) conv-w repack, [576,688) gemm-w repack, [688,944) x transpose (img x 8 cc)
__global__ __launch_bounds__(256) void setup_k(
    const float* __restrict__ x, const float* __restrict__ c1w, const float* __restrict__ c2w,
    const float* __restrict__ wq, const float* __restrict__ wo,
    const float* __restrict__ w1, const float* __restrict__ w2,
    unsigned short* __restrict__ wp1, unsigned short* __restrict__ wp2,
    unsigned short* __restrict__ pq, unsigned short* __restrict__ po,
    unsigned short* __restrict__ p1, unsigned short* __restrict__ p2,
    unsigned short* __restrict__ xtp, unsigned short* __restrict__ o1p)
{
    int blk = blockIdx.x, tid = threadIdx.x;
    if (blk < 576) {
        const float* src = (blk < 288) ? c1w : c2w;
        unsigned short* dst = (blk < 288) ? wp1 : wp2;
        int f = (blk % 288) * 256 + tid;
        int lane = f & 63, s = f >> 6;
        int t = s >> 7, rem = s & 127, kc = rem >> 4, ntg = rem & 15;
        int co = ntg * 16 + (lane & 15);
        int ci0 = kc * 32 + ((lane >> 4) << 3);
        unsigned short v[8];
#pragma unroll
        for (int j = 0; j < 8; ++j) v[j] = f2b(src[((size_t)co * 256 + ci0 + j) * 9 + t]);
        u32x4 q;
        q.x = (unsigned)v[0] | ((unsigned)v[1] << 16);
        q.y = (unsigned)v[2] | ((unsigned)v[3] << 16);
        q.z = (unsigned)v[4] | ((unsigned)v[5] << 16);
        q.w = (unsigned)v[6] | ((unsigned)v[7] << 16);
        *(u32x4*)(dst + (size_t)f * 8) = q;
    } else if (blk < 688) {
        int f = (blk - 576) * 256 + tid;   // 0..28671
        const float* src; unsigned short* dst; int NTT, lf;
        if (f < 2048)       { src = wq; dst = pq; NTT = 4;  lf = f; }
        else if (f < 4096)  { src = wo; dst = po; NTT = 16; lf = f - 2048; }
        else if (f < 20480) { src = w1; dst = p1; NTT = 32; lf = f - 4096; }
        else                { src = w2; dst = p2; NTT = 16; lf = f - 20480; }
        int lane = lf & 63, s = lf >> 6;
        int kc = s / NTT, ntg = s % NTT;
        int N = NTT * 16;
        int k0 = kc * 32 + ((lane >> 4) << 3), n = ntg * 16 + (lane & 15);
        unsigned short v[8];
#pragma unroll
        for (int j = 0; j < 8; ++j) v[j] = f2b(src[(size_t)(k0 + j) * N + n]);
        u32x4 q;
        q.x = (unsigned)v[0] | ((unsigned)v[1] << 16);
        q.y = (unsigned)v[2] | ((unsigned)v[3] << 16);
        q.z = (unsigned)v[4] | ((unsigned)v[5] << 16);
        q.w = (unsigned)v[6] | ((unsigned)v[7] << 16);
        *(u32x4*)(dst + (size_t)lf * 8) = q;
    } else {
        int t = blk - 688;                 // 0..255 : img(32) x cc(8)
        int img = t >> 3, cc = t & 7;
        int h = tid >> 4, w = tid & 15;
        unsigned short* dst = xtp + ((size_t)img * 324 + (h + 1) * 18 + (w + 1)) * 256 + cc * 32;
        const float* src = x + (size_t)img * 65536 + (size_t)cc * 32 * 256 + tid;
        unsigned short v[32];
#pragma unroll
        for (int j = 0; j < 32; ++j) v[j] = f2b(src[j * 256]);
        u32x4* dp = (u32x4*)dst;
#pragma unroll
        for (int i = 0; i < 4; ++i) {
            u32x4 q;
            q.x = (unsigned)v[i*8+0] | ((unsigned)v[i*8+1] << 16);
            q.y = (unsigned)v[i*8+2] | ((unsigned)v[i*8+3] << 16);
            q.z = (unsigned)v[i*8+4] | ((unsigned)v[i*8+5] << 16);
            q.w = (unsigned)v[i*8+6] | ((unsigned)v[i*8+7] << 16);
            dp[i] = q;
        }
        // each cc-block zeroes its own 64B channel slice of the halo cells
        for (int cell = tid; cell < 324; cell += 256) {
            int hh = cell / 18, ww = cell - hh * 18;
            if (hh == 0 || hh == 17 || ww == 0 || ww == 17) {
                u32x4 z = (u32x4)0u;
                u32x4* zp1 = (u32x4*)(xtp + ((size_t)img * 324 + cell) * 256 + cc * 32);
                u32x4* zp2 = (u32x4*)(o1p + ((size_t)img * 324 + cell) * 256 + cc * 32);
#pragma unroll
                for (int i = 0; i < 4; ++i) { zp1[i] = z; zp2[i] = z; }
            }
        }
    }
}

// ================ conv: 9-tap implicit GEMM, 64x64 tile, K-split x4 (R2, verified) ================
template<int EPI>
__global__ __launch_bounds__(256, 2) void conv_mfma(const unsigned short* __restrict__ Asrc,
                                                    const unsigned short* __restrict__ wpack,
                                                    const float* __restrict__ bng,
                                                    const float* __restrict__ bnb,
                                                    const unsigned short* __restrict__ resid,
                                                    unsigned short* __restrict__ outP,
                                                    float* __restrict__ outT)
{
    __shared__ __align__(16) float part[4][4][4][64][4];   // [wave][mt][nt][lane][r] = 64 KB
    int blk = blockIdx.x;                   // 512 blocks
    int img = blk >> 4, rem = blk & 15;
    int mo = rem >> 2, nq = rem & 3;
    int tid = threadIdx.x;
    int wv = tid >> 6, lane = tid & 63;
    int lq = lane >> 4, lr = lane & 15;
    int m0 = mo * 64;
    int n0 = nq * 64;

    f32x4 acc[4][4];
#pragma unroll
    for (int i = 0; i < 4; ++i)
#pragma unroll
        for (int j = 0; j < 4; ++j) acc[i][j] = 0.f;

    int abase[4];
#pragma unroll
    for (int mt = 0; mt < 4; ++mt) {
        int m = m0 + mt * 16 + lr;
        int h = m >> 4, w = m & 15;
        abase[mt] = (img * 324 + (h + 1) * 18 + (w + 1)) * 256 + lq * 8;
    }
    int bb0 = (n0 >> 4) * 512 + lane * 8;

    for (int kc2 = 0; kc2 < 2; ++kc2) {
        int kc = wv * 2 + kc2;
#pragma unroll
        for (int tap = 0; tap < 9; ++tap) {
            int dh = tap / 3 - 1, dw = tap % 3 - 1;
            int aoff = (dh * 18 + dw) * 256 + kc * 32;
            bf16x8 a[4], b[4];
#pragma unroll
            for (int mt = 0; mt < 4; ++mt) a[mt] = *(const bf16x8*)(Asrc + abase[mt] + aoff);
            int boff = (tap * 8 + kc) * 8192 + bb0;
#pragma unroll
            for (int nt = 0; nt < 4; ++nt) b[nt] = *(const bf16x8*)(wpack + boff + nt * 512);
#pragma unroll
            for (int mt = 0; mt < 4; ++mt)
#pragma unroll
                for (int nt = 0; nt < 4; ++nt)
                    acc[mt][nt] = __builtin_amdgcn_mfma_f32_16x16x32_bf16(a[mt], b[nt], acc[mt][nt], 0, 0, 0);
        }
    }
    // publish partials
#pragma unroll
    for (int mt = 0; mt < 4; ++mt)
#pragma unroll
        for (int nt = 0; nt < 4; ++nt)
            *(f32x4*)&part[wv][mt][nt][lane][0] = acc[mt][nt];
    __syncthreads();
    // wave wv combines + epilogues quadrant mt = wv
    int mt = wv;
#pragma unroll
    for (int nt = 0; nt < 4; ++nt) {
        f32x4 s0 = *(const f32x4*)&part[0][mt][nt][lane][0];
        f32x4 s1 = *(const f32x4*)&part[1][mt][nt][lane][0];
        f32x4 s2 = *(const f32x4*)&part[2][mt][nt][lane][0];
        f32x4 s3 = *(const f32x4*)&part[3][mt][nt][lane][0];
        f32x4 sum;
#pragma unroll
        for (int r = 0; r < 4; ++r) sum[r] = (s0[r] + s1[r]) + (s2[r] + s3[r]);
        int co = n0 + nt * 16 + lr;
        float g = bng[co], bb = bnb[co];
#pragma unroll
        for (int r = 0; r < 4; ++r) {
            int m = m0 + mt * 16 + lq * 4 + r;
            int h = m >> 4, w = m & 15;
            float v = sum[r] * g + bb;
            if (EPI == 0) {
                v = fmaxf(v, 0.f);
                outP[((size_t)img * 324 + (h + 1) * 18 + (w + 1)) * 256 + co] = f2b(v);
            } else {
                v += b2f(resid[((size_t)img * 324 + (h + 1) * 18 + (w + 1)) * 256 + co]);
                v = fmaxf(v, 0.f);
                outT[((size_t)img * 256 + m) * 256 + co] = v;
            }
        }
    }
}

// ================ fused LN(t) + q-GEMM + e0 (R9, passed) ================
__global__ __launch_bounds__(256) void lnq_k(
    const float* __restrict__ t, const float* __restrict__ g, const float* __restrict__ bta,
    const unsigned short* __restrict__ bpq, const float* __restrict__ wqe,
    unsigned short* __restrict__ qb, unsigned short* __restrict__ e0p)
{
    __shared__ __align__(16) unsigned int frag[64 * 132];   // 33792 B
    __shared__ float qrow[64];
    int bx = blockIdx.x, tid = threadIdx.x;
    int wv = tid >> 6, lane = tid & 63;
    int c = lane * 4;
    f32x4 gv = *(const f32x4*)(g + c);
    f32x4 bv = *(const f32x4*)(bta + c);
#pragma unroll
    for (int p = 0; p < 16; ++p) {
        int rl = wv * 16 + p;
        f32x4 x = *(const f32x4*)(t + (size_t)(bx * 64 + rl) * 256 + c);
        float s  = x[0] + x[1] + x[2] + x[3];
        float ss = x[0]*x[0] + x[1]*x[1] + x[2]*x[2] + x[3]*x[3];
#pragma unroll
        for (int off = 32; off >= 1; off >>= 1) { s += __shfl_xor(s, off); ss += __shfl_xor(ss, off); }
        float mean = s * (1.f / 256.f);
        float var  = ss * (1.f / 256.f) - mean * mean;
        float rstd = rsqrtf(fmaxf(var, 0.f) + 1e-5f);
        float y0 = (x[0]-mean)*rstd*gv[0] + bv[0];
        float y1 = (x[1]-mean)*rstd*gv[1] + bv[1];
        float y2 = (x[2]-mean)*rstd*gv[2] + bv[2];
        float y3 = (x[3]-mean)*rstd*gv[3] + bv[3];
        frag[rl * 132 + 2 * lane]     = pack2(y0, y1);
        frag[rl * 132 + 2 * lane + 1] = pack2(y2, y3);
    }
    __syncthreads();
    int lq = lane >> 4, lr = lane & 15;
    f32x4 acc[4];
#pragma unroll
    for (int nt = 0; nt < 4; ++nt) acc[nt] = 0.f;
    const short* sA = (const short*)frag;
#pragma unroll
    for (int kc = 0; kc < 8; ++kc) {
        bf16x8 a = *(const bf16x8*)(sA + (wv * 16 + lr) * 264 + kc * 32 + lq * 8);
#pragma unroll
        for (int nt = 0; nt < 4; ++nt) {
            bf16x8 bfr = *(const bf16x8*)(bpq + (size_t)(kc * 4 + nt) * 512 + lane * 8);
            acc[nt] = __builtin_amdgcn_mfma_f32_16x16x32_bf16(a, bfr, acc[nt], 0, 0, 0);
        }
    }
#pragma unroll
    for (int nt = 0; nt < 4; ++nt)
#pragma unroll
        for (int r = 0; r < 4; ++r)
            qb[(size_t)(bx * 64 + wv * 16 + lq * 4 + r) * 64 + nt * 16 + lr] = f2b(acc[nt][r]);
    if ((bx & 3) == 0 && wv == 0 && lq == 0) {
#pragma unroll
        for (int nt = 0; nt < 4; ++nt) qrow[nt * 16 + lr] = acc[nt][0];
    }
    __syncthreads();
    if ((bx & 3) == 0) {
        int b = bx >> 2;
        int r = tid;
        float a2 = 0.f;
#pragma unroll 8
        for (int d = 0; d < 64; ++d) a2 += qrow[d] * wqe[d * 256 + r];
        int nt = b >> 4, kc = r >> 5;
        int ln_ = (b & 15) + (((r >> 3) & 3) << 4);
        int j = r & 7;
        e0p[(((nt * 8 + kc) * 64) + ln_) * 8 + j] = f2b(a2);
    }
}

// ================ fused ctx-LN + dist GEMM v4 (R8, verified) ================
__global__ __launch_bounds__(256, 4) void lndist_k(
    const float* __restrict__ ctx, const float* __restrict__ lgam, const float* __restrict__ lbet,
    const unsigned short* __restrict__ e0p, float* __restrict__ dist)
{
    __shared__ __align__(16) unsigned int frag[32 * 132];
    __shared__ __align__(16) float rn2s[32];
    int r0 = blockIdx.x * 32;
    int tid = threadIdx.x;
    int wv = tid >> 6, lane = tid & 63;

    float2 d0[8], d1[8], d2[8];
    const float* base = ctx + (size_t)(r0 + wv * 8) * 266;
#pragma unroll
    for (int p = 0; p < 8; ++p) {
        const float* rowp = base + p * 266;
        d0[p] = *(const float2*)(rowp + 2 * lane);
        d1[p] = *(const float2*)(rowp + 128 + 2 * lane);
        if (lane < 5) d2[p] = *(const float2*)(rowp + 256 + 2 * lane);
        else { d2[p].x = 0.f; d2[p].y = 0.f; }
    }
    float2 g0 = *(const float2*)(lgam + 2 * lane);
    float2 g1 = *(const float2*)(lgam + 128 + 2 * lane);
    float2 b0 = *(const float2*)(lbet + 2 * lane);
    float2 b1 = *(const float2*)(lbet + 128 + 2 * lane);

#pragma unroll
    for (int p = 0; p < 8; ++p) {
        int rl = wv * 8 + p;
        float s  = d0[p].x + d0[p].y + d1[p].x + d1[p].y + d2[p].x + d2[p].y;
        float ss = d0[p].x*d0[p].x + d0[p].y*d0[p].y + d1[p].x*d1[p].x + d1[p].y*d1[p].y
                 + d2[p].x*d2[p].x + d2[p].y*d2[p].y;
#pragma unroll
        for (int off = 32; off >= 1; off >>= 1) { s += __shfl_xor(s, off); ss += __shfl_xor(ss, off); }
        float mean = s * (1.f / 266.f);
        float var  = ss * (1.f / 266.f) - mean * mean;
        float rstd = rsqrtf(fmaxf(var, 0.f) + 1e-5f);
        float c0 = (d0[p].x - mean) * rstd * g0.x + b0.x;
        float c1 = (d0[p].y - mean) * rstd * g0.y + b0.y;
        float c2 = (d1[p].x - mean) * rstd * g1.x + b1.x;
        float c3 = (d1[p].y - mean) * rstd * g1.y + b1.y;
        frag[rl * 132 + lane]      = pack2(c0, c1);
        frag[rl * 132 + 64 + lane] = pack2(c2, c3);
        float nsq = c0*c0 + c1*c1 + c2*c2 + c3*c3;
#pragma unroll
        for (int off = 32; off >= 1; off >>= 1) nsq += __shfl_xor(nsq, off);
        if (lane == 0) rn2s[rl] = nsq;
    }
    __syncthreads();

    int lq = lane >> 4, lr = lane & 15;
    int rt = wv & 1, ch = wv >> 1;
    f32x4 acc = 0.f;
    const short* sA = (const short*)frag;
#pragma unroll
    for (int kc = 0; kc < 8; ++kc) {
        bf16x8 a = *(const bf16x8*)(sA + (rt * 16 + lr) * 264 + kc * 32 + lq * 8);
        bf16x8 b = *(const bf16x8*)(e0p + ((ch * 8 + kc) * 64 + lane) * 8);
        acc = __builtin_amdgcn_mfma_f32_16x16x32_bf16(a, b, acc, 0, 0, 0);
    }
    int mbase = r0 + rt * 16 + lq * 4;
    f32x4 rv = *(f32x4*)(rn2s + rt * 16 + lq * 4);
    f32x4 o;
#pragma unroll
    for (int r = 0; r < 4; ++r) o[r] = rv[r] - 2.f * acc[r];
    *(f32x4*)(dist + (size_t)(ch * 16 + lr) * 100000 + mbase) = o;
}

// ================ top-32 stage 1: register-resident slices, no LDS ================
// grid (16,32): block = (chunk c, batch b). Wave w owns strip [w*1600, w*1600+1600)
// of the 6250-element chunk; each lane keeps 25 elements in VGPRs. 32 iterations of
// {12-shuffle butterfly argmin; owner lane masks + rescans its registers}.
// Same scan order / strict-< tie rules as the LDS rescan version -> identical output.
__global__ __launch_bounds__(256) void topk1w(const float* __restrict__ dist,
                                              float* __restrict__ candv,
                                              int* __restrict__ candi)
{
    int c = blockIdx.x, b = blockIdx.y;
    int tid = threadIdx.x;
    int wv = tid >> 6, lane = tid & 63;
    int base = wv * 1600;
    const float* src = dist + (size_t)b * 100000 + c * 6250 + base;
    float v[25];
#pragma unroll
    for (int t = 0; t < 25; ++t) {
        int i = lane + t * 64;
        v[t] = (base + i < 6250) ? src[i] : 3e38f;
    }
    float lm = v[0]; int lt = 0;
#pragma unroll
    for (int t = 1; t < 25; ++t) if (v[t] < lm) { lm = v[t]; lt = t; }
    float* cvp = candv + (((size_t)b * 16 + c) * 4 + wv) * 32;
    int*   cip = candi + (((size_t)b * 16 + c) * 4 + wv) * 32;
    for (int it = 0; it < 32; ++it) {
        float gm = lm;
        int gmeta = (lane << 5) | lt;      // lane<64, t<32
#pragma unroll
        for (int off = 32; off >= 1; off >>= 1) {
            float ov = __shfl_xor(gm, off);
            int om = __shfl_xor(gmeta, off);
            if (ov < gm) { gm = ov; gmeta = om; }
        }
        int gl = gmeta >> 5, gt = gmeta & 31;
        if (lane == 0) {
            cvp[it] = gm;
            cip[it] = c * 6250 + base + gl + gt * 64;
        }
        if (lane == gl) {
#pragma unroll
            for (int t = 0; t < 25; ++t) if (t == gt) v[t] = 3e38f;
            lm = v[0]; lt = 0;
#pragma unroll
            for (int t = 1; t < 25; ++t) if (v[t] < lm) { lm = v[t]; lt = t; }
        }
    }
}

// ================ selection stage 2 + gather + LN + k/v projections (fused) ================
// 32 blocks (one per batch). Phase 1: register-resident hierarchical exact top-32 of
// 2048 candidates (per-wave 512->32, wave0 merges 128->32, ascending order preserved).
// Phase 2: gather rows, LN into LDS. Phase 3: k/v matvec with wk-load reuse.
__global__ __launch_bounds__(256) void selkv_k(const float* __restrict__ candv,
                                               const int* __restrict__ candi,
                                               const float* __restrict__ ctx,
                                               const float* __restrict__ g,
                                               const float* __restrict__ bta,
                                               const float* __restrict__ wk,
                                               const float* __restrict__ wvm,
                                               float* __restrict__ kb,
                                               float* __restrict__ vb)
{
    __shared__ float fv[128];  __shared__ int fi[128];
    __shared__ int rows[32];
    __shared__ float cnv[32][268];
    int b = blockIdx.x, tid = threadIdx.x;
    int wv = tid >> 6, lane = tid & 63;
    // wave-level: top-32 of each 512-candidate strip (8 regs/lane)
    {
        const float* cvb = candv + (size_t)b * 2048 + wv * 512;
        const int*   cib = candi + (size_t)b * 2048 + wv * 512;
        float v8[8]; int id8[8];
#pragma unroll
        for (int t = 0; t < 8; ++t) { v8[t] = cvb[lane + t * 64]; id8[t] = cib[lane + t * 64]; }
        float lm = v8[0]; int lt = 0, lid = id8[0];
#pragma unroll
        for (int t = 1; t < 8; ++t) if (v8[t] < lm) { lm = v8[t]; lt = t; lid = id8[t]; }
        for (int it = 0; it < 32; ++it) {
            float gm = lm; int gid = lid;
            int gmeta = (lane << 3) | lt;
#pragma unroll
            for (int off = 32; off >= 1; off >>= 1) {
                float ov = __shfl_xor(gm, off);
                int oi = __shfl_xor(gid, off);
                int om = __shfl_xor(gmeta, off);
                if (ov < gm) { gm = ov; gid = oi; gmeta = om; }
            }
            int gl = gmeta >> 3, gt = gmeta & 7;
            if (lane == 0) { fv[wv * 32 + it] = gm; fi[wv * 32 + it] = gid; }
            if (lane == gl) {
#pragma unroll
                for (int t = 0; t < 8; ++t) if (t == gt) v8[t] = 3e38f;
                lm = v8[0]; lt = 0; lid = id8[0];
#pragma unroll
                for (int t = 1; t < 8; ++t) if (v8[t] < lm) { lm = v8[t]; lt = t; lid = id8[t]; }
            }
        }
    }
    __syncthreads();
    // wave 0 merges 128 -> 32 (ascending), 2 regs/lane
    if (wv == 0) {
        float v2[2]; int id2[2];
#pragma unroll
        for (int t = 0; t < 2; ++t) { v2[t] = fv[lane + t * 64]; id2[t] = fi[lane + t * 64]; }
        float lm = v2[0]; int lt = 0, lid = id2[0];
        if (v2[1] < lm) { lm = v2[1]; lt = 1; lid = id2[1]; }
        for (int it = 0; it < 32; ++it) {
            float gm = lm; int gid = lid;
            int gmeta = (lane << 1) | lt;
#pragma unroll
            for (int off = 32; off >= 1; off >>= 1) {
                float ov = __shfl_xor(gm, off);
                int oi = __shfl_xor(gid, off);
                int om = __shfl_xor(gmeta, off);
                if (ov < gm) { gm = ov; gid = oi; gmeta = om; }
            }
            int gl = gmeta >> 1, gt = gmeta & 1;
            if (lane == 0) rows[it] = gid;
            if (lane == gl) {
#pragma unroll
                for (int t = 0; t < 2; ++t) if (t == gt) v2[t] = 3e38f;
                lm = v2[0]; lt = 0; lid = id2[0];
                if (v2[1] < lm) { lm = v2[1]; lt = 1; lid = id2[1]; }
            }
        }
    }
    __syncthreads();
    // gather + LN: wave w handles rows j = w*8 .. w*8+7
    for (int p = 0; p < 8; ++p) {
        int j = wv * 8 + p;
        int rrow = rows[j];
        const float* pp = ctx + (size_t)rrow * 266;
        float2 a0 = *(const float2*)(pp + 2 * lane);
        float2 a1 = *(const float2*)(pp + 128 + 2 * lane);
        float x4 = 0.f, x5 = 0.f;
        if (lane < 5) { float2 a2 = *(const float2*)(pp + 256 + 2 * lane); x4 = a2.x; x5 = a2.y; }
        float s  = a0.x + a0.y + a1.x + a1.y + x4 + x5;
        float ss = a0.x*a0.x + a0.y*a0.y + a1.x*a1.x + a1.y*a1.y + x4*x4 + x5*x5;
#pragma unroll
        for (int off = 32; off >= 1; off >>= 1) { s += __shfl_xor(s, off); ss += __shfl_xor(ss, off); }
        float mean = s * (1.f / 266.f);
        float var  = ss * (1.f / 266.f) - mean * mean;
        float rstd = rsqrtf(fmaxf(var, 0.f) + 1e-5f);
        float2 g0 = *(const float2*)(g + 2 * lane);
        float2 g1 = *(const float2*)(g + 128 + 2 * lane);
        float2 b0 = *(const float2*)(bta + 2 * lane);
        float2 b1 = *(const float2*)(bta + 128 + 2 * lane);
        cnv[j][2*lane]       = (a0.x - mean) * rstd * g0.x + b0.x;
        cnv[j][2*lane + 1]   = (a0.y - mean) * rstd * g0.y + b0.y;
        cnv[j][128 + 2*lane] = (a1.x - mean) * rstd * g1.x + b1.x;
        cnv[j][129 + 2*lane] = (a1.y - mean) * rstd * g1.y + b1.y;
        if (lane < 5) {
            float2 g2 = *(const float2*)(g + 256 + 2 * lane);
            float2 b2 = *(const float2*)(bta + 256 + 2 * lane);
            cnv[j][256 + 2*lane] = (x4 - mean) * rstd * g2.x + b2.x;
            cnv[j][257 + 2*lane] = (x5 - mean) * rstd * g2.y + b2.y;
        }
    }
    __syncthreads();
    // k projection: wave w computes rows j = w*8..w*8+7, col = lane; reuse wk loads across 8 rows
    {
        float acc[8];
#pragma unroll
        for (int p = 0; p < 8; ++p) acc[p] = 0.f;
        int j0 = wv * 8;
        for (int r = 0; r < 256; r += 4) {
            float w0 = wk[(r + 0) * 64 + lane];
            float w1_ = wk[(r + 1) * 64 + lane];
            float w2_ = wk[(r + 2) * 64 + lane];
            float w3 = wk[(r + 3) * 64 + lane];
#pragma unroll
            for (int p = 0; p < 8; ++p) {
                f32x4 cv = *(const f32x4*)&cnv[j0 + p][r];
                acc[p] += cv[0] * w0 + cv[1] * w1_ + cv[2] * w2_ + cv[3] * w3;
            }
        }
#pragma unroll
        for (int p = 0; p < 8; ++p)
            kb[((size_t)b * 32 + j0 + p) * 64 + lane] = acc[p];
        // v projection (10-dim)
#pragma unroll
        for (int p = 0; p < 8; ++p) {
            float a2 = 0.f;
#pragma unroll
            for (int r = 0; r < 10; ++r) a2 += cnv[j0 + p][256 + r] * wvm[r * 64 + lane];
            vb[((size_t)b * 32 + j0 + p) * 64 + lane] = a2;
        }
    }
}

// ================ tail: attention + wo GEMM + LN + ff1/GeGLU + ff2 + residuals + store ================
// 256 blocks x 32 rows (one batch-px-slab each). Attention computed inline (bit-identical
// to the old attn_k inner loop, 4 passes of 8 px), o kept in LDS as bf16; t2/xn2/u never
// leave LDS.
__global__ __launch_bounds__(256) void tail_k(
    const unsigned short* __restrict__ qg,   // q [8192][64] bf16
    const float* __restrict__ kbuf,          // k [32][32][64] f32
    const float* __restrict__ vbuf,          // v [32][32][64] f32
    const unsigned short* __restrict__ Bpo,  // wo packed (NTT=16)
    const float* __restrict__ bo, const float* __restrict__ tres,
    const float* __restrict__ lng, const float* __restrict__ lnb,
    const unsigned short* __restrict__ Bp1, const float* __restrict__ b1, // w1 packed (NTT=32)
    const unsigned short* __restrict__ Bp2, const float* __restrict__ b2, // w2 packed (NTT=16)
    float* __restrict__ out)
{
    __shared__ __align__(16) float tile[32 * 268];          // attn staging -> wo acc -> t2 -> ff2 result
    __shared__ __align__(16) unsigned short xt[32 * 264];   // attn-o (bf16) -> LN out -> u
    int m0 = blockIdx.x * 32;
    int tid = threadIdx.x, wv = tid >> 6, lane = tid & 63, lq = lane >> 4, lr = lane & 15;
    int n0 = wv * 64;
    const short* xts = (const short*)xt;
    int b = m0 >> 8, px0 = m0 & 255;

    // ---- phase 0: attention for the 32 px of this block ----
    {
        float* kl = tile;            // [32][66]
        float* vl = tile + 2112;     // [32][66]
        float* ql = tile + 4224;     // [32][64]
        float* pl = tile + 6272;     // [8][32] per pass (wave-private rows)
        for (int i = tid; i < 2048; i += 256) {
            int row = i >> 6, d = i & 63;
            kl[row * 66 + d] = kbuf[(size_t)b * 2048 + i];
            vl[row * 66 + d] = vbuf[(size_t)b * 2048 + i];
        }
        for (int i = tid; i < 2048; i += 256) {
            ql[i] = b2f(qg[((size_t)b * 256 + px0) * 64 + i]);
        }
        __syncthreads();
        int lp = wv * 2 + (lane >> 5);
        int j = lane & 31;
#pragma unroll
        for (int pass = 0; pass < 4; ++pass) {
            int px = pass * 8 + lp;
            const float* qp = ql + px * 64;
            const float* kp = kl + j * 66;
            float s = 0.f;
#pragma unroll
            for (int d = 0; d < 64; ++d) s += qp[d] * kp[d];
            s *= 0.125f;
            float mx = s;
#pragma unroll
            for (int off = 16; off >= 1; off >>= 1) mx = fmaxf(mx, __shfl_xor(mx, off));
            float p = expf(s - mx);
            float sum = p;
#pragma unroll
            for (int off = 16; off >= 1; off >>= 1) sum += __shfl_xor(sum, off);
            p /= sum;
            pl[lp * 32 + j] = p;
            int d0 = 2 * j;
            float o0 = 0.f, o1 = 0.f;
#pragma unroll
            for (int jj = 0; jj < 32; ++jj) {
                float pj = pl[lp * 32 + jj];
                float2 vv = *(const float2*)(vl + jj * 66 + d0);
                o0 += pj * vv.x;
                o1 += pj * vv.y;
            }
            *(unsigned int*)(xt + px * 264 + d0) = pack2(o0, o1);
        }
    }
    __syncthreads();

    // ---- phase A: wo GEMM (K=64), A from xt, wave w -> cols n0..n0+64 ----
    {
        f32x4 acc[2][4];
#pragma unroll
        for (int i = 0; i < 2; ++i)
#pragma unroll
            for (int j = 0; j < 4; ++j) acc[i][j] = 0.f;
#pragma unroll
        for (int kc = 0; kc < 2; ++kc) {
            bf16x8 a0 = *(const bf16x8*)(xts + lr * 264 + kc * 32 + lq * 8);
            bf16x8 a1 = *(const bf16x8*)(xts + (16 + lr) * 264 + kc * 32 + lq * 8);
#pragma unroll
            for (int nt = 0; nt < 4; ++nt) {
                bf16x8 bfr = *(const bf16x8*)(Bpo + (size_t)(kc * 16 + (n0 >> 4) + nt) * 512 + lane * 8);
                acc[0][nt] = __builtin_amdgcn_mfma_f32_16x16x32_bf16(a0, bfr, acc[0][nt], 0, 0, 0);
                acc[1][nt] = __builtin_amdgcn_mfma_f32_16x16x32_bf16(a1, bfr, acc[1][nt], 0, 0, 0);
            }
        }
        __syncthreads();   // tile attn-staging reads done (phase 0 data dead), xt reads done
#pragma unroll
        for (int mt = 0; mt < 2; ++mt)
#pragma unroll
            for (int nt = 0; nt < 4; ++nt)
#pragma unroll
                for (int r = 0; r < 4; ++r)
                    tile[(mt * 16 + lq * 4 + r) * 268 + n0 + nt * 16 + lr] = acc[mt][nt][r];
    }
    __syncthreads();

    // ---- phase B: + bias + residual -> t2 (back into tile); LN -> xt (bf16) ----
    {
        int row = tid >> 3, c0 = (tid & 7) * 32;
        const float* trp = tres + (size_t)(m0 + row) * 256 + c0;
        float v[32];
#pragma unroll
        for (int i = 0; i < 8; ++i) {
            f32x4 t4 = *(f32x4*)(tile + row * 268 + c0 + i * 4);
            f32x4 rr = *(const f32x4*)(trp + i * 4);
            f32x4 bb = *(const f32x4*)(bo + c0 + i * 4);
#pragma unroll
            for (int k = 0; k < 4; ++k) v[i*4+k] = t4[k] + rr[k] + bb[k];
        }
#pragma unroll
        for (int i = 0; i < 8; ++i) {
            f32x4 o; o[0] = v[i*4]; o[1] = v[i*4+1]; o[2] = v[i*4+2]; o[3] = v[i*4+3];
            *(f32x4*)(tile + row * 268 + c0 + i * 4) = o;   // t2
        }
        float s = 0.f, ss = 0.f;
#pragma unroll
        for (int i = 0; i < 32; ++i) { s += v[i]; ss += v[i] * v[i]; }
#pragma unroll
        for (int off = 1; off <= 4; off <<= 1) { s += __shfl_xor(s, off); ss += __shfl_xor(ss, off); }
        float mean = s * (1.f / 256.f);
        float var  = ss * (1.f / 256.f) - mean * mean;
        float rstd = rsqrtf(fmaxf(var, 0.f) + 1e-5f);
        unsigned int pk[16];
#pragma unroll
        for (int i = 0; i < 16; ++i) {
            float y0 = (v[2*i]   - mean) * rstd * lng[c0+2*i]   + lnb[c0+2*i];
            float y1 = (v[2*i+1] - mean) * rstd * lng[c0+2*i+1] + lnb[c0+2*i+1];
            pk[i] = pack2(y0, y1);
        }
        u32x4* dp = (u32x4*)(xt + row * 264 + c0);
#pragma unroll
        for (int i = 0; i < 4; ++i) {
            u32x4 o; o.x = pk[i*4]; o.y = pk[i*4+1]; o.z = pk[i*4+2]; o.w = pk[i*4+3];
            dp[i] = o;
        }
    }
    __syncthreads();

    // ---- phase C: ff1 (K=256). wave w -> a-cols [n0,n0+64), g-cols [256+n0, ...) ----
    f32x4 fa[2][4], fg[2][4];
#pragma unroll
    for (int i = 0; i < 2; ++i)
#pragma unroll
        for (int j = 0; j < 4; ++j) { fa[i][j] = 0.f; fg[i][j] = 0.f; }
#pragma unroll
    for (int kc = 0; kc < 8; ++kc) {
        bf16x8 a0 = *(const bf16x8*)(xts + lr * 264 + kc * 32 + lq * 8);
        bf16x8 a1 = *(const bf16x8*)(xts + (16 + lr) * 264 + kc * 32 + lq * 8);
#pragma unroll
        for (int nt = 0; nt < 4; ++nt) {
            bf16x8 bA = *(const bf16x8*)(Bp1 + (size_t)(kc * 32 + (n0 >> 4) + nt) * 512 + lane * 8);
            bf16x8 bG = *(const bf16x8*)(Bp1 + (size_t)(kc * 32 + 16 + (n0 >> 4) + nt) * 512 + lane * 8);
            fa[0][nt] = __builtin_amdgcn_mfma_f32_16x16x32_bf16(a0, bA, fa[0][nt], 0, 0, 0);
            fa[1][nt] = __builtin_amdgcn_mfma_f32_16x16x32_bf16(a1, bA, fa[1][nt], 0, 0, 0);
            fg[0][nt] = __builtin_amdgcn_mfma_f32_16x16x32_bf16(a0, bG, fg[0][nt], 0, 0, 0);
            fg[1][nt] = __builtin_amdgcn_mfma_f32_16x16x32_bf16(a1, bG, fg[1][nt], 0, 0, 0);
        }
    }
    __syncthreads();   // all xt reads done
    // GeGLU -> u into xt
#pragma unroll
    for (int nt = 0; nt < 4; ++nt) {
        int col = n0 + nt * 16 + lr;
        float ba = b1[col], bg = b1[256 + col];
#pragma unroll
        for (int mt = 0; mt < 2; ++mt)
#pragma unroll
            for (int r = 0; r < 4; ++r) {
                float a = fa[mt][nt][r] + ba;
                float gg = fg[mt][nt][r] + bg;
                xt[(mt * 16 + lq * 4 + r) * 264 + col] = f2b(a * gelu_exact(gg));
            }
    }
    __syncthreads();

    // ---- phase D: ff2 (K=256). wave w -> cols n0..n0+64; += b2 + t2; in-place into tile ----
    {
        f32x4 c2[2][4];
#pragma unroll
        for (int i = 0; i < 2; ++i)
#pragma unroll
            for (int j = 0; j < 4; ++j) c2[i][j] = 0.f;
#pragma unroll
        for (int kc = 0; kc < 8; ++kc) {
            bf16x8 a0 = *(const bf16x8*)(xts + lr * 264 + kc * 32 + lq * 8);
            bf16x8 a1 = *(const bf16x8*)(xts + (16 + lr) * 264 + kc * 32 + lq * 8);
#pragma unroll
            for (int nt = 0; nt < 4; ++nt) {
                bf16x8 bfr = *(const bf16x8*)(Bp2 + (size_t)(kc * 16 + (n0 >> 4) + nt) * 512 + lane * 8);
                c2[0][nt] = __builtin_amdgcn_mfma_f32_16x16x32_bf16(a0, bfr, c2[0][nt], 0, 0, 0);
                c2[1][nt] = __builtin_amdgcn_mfma_f32_16x16x32_bf16(a1, bfr, c2[1][nt], 0, 0, 0);
            }
        }
#pragma unroll
        for (int nt = 0; nt < 4; ++nt) {
            int col = n0 + nt * 16 + lr;
            float bv = b2[col];
#pragma unroll
            for (int mt = 0; mt < 2; ++mt)
#pragma unroll
                for (int r = 0; r < 4; ++r) {
                    int m = mt * 16 + lq * 4 + r;
                    tile[m * 268 + col] = c2[mt][nt][r] + bv + tile[m * 268 + col];
                }
        }
    }
    __syncthreads();

    // ---- transposed store: out[b][c][px0..px0+32) ----
    {
        int c = tid;
        float* dp = out + ((size_t)b * 256 + c) * 256 + px0;
#pragma unroll
        for (int q = 0; q < 8; ++q) {
            f32x4 o;
            o[0] = tile[(q * 4 + 0) * 268 + c];
            o[1] = tile[(q * 4 + 1) * 268 + c];
            o[2] = tile[(q * 4 + 2) * 268 + c];
            o[3] = tile[(q * 4 + 3) * 268 + c];
            *(f32x4*)(dp + q * 4) = o;
        }
    }
}

// ================ launch ================
extern "C" void kernel_launch(void* const* d_in, const int* in_sizes, int n_in,
                              void* d_out, int out_size, void* d_ws, size_t ws_size,
                              hipStream_t stream)
{
    (void)in_sizes; (void)n_in; (void)out_size; (void)ws_size;
    const float* x    = (const float*)d_in[0];
    const float* c1w  = (const float*)d_in[1];
    const float* c2w  = (const float*)d_in[2];
    const float* bn1g = (const float*)d_in[3];
    const float* bn1b = (const float*)d_in[4];
    const float* bn2g = (const float*)d_in[5];
    const float* bn2b = (const float*)d_in[6];
    const float* rdat = (const float*)d_in[7];
    const float* lag  = (const float*)d_in[8];
    const float* labp = (const float*)d_in[9];
    const float* lcg  = (const float*)d_in[10];
    const float* lcb  = (const float*)d_in[11];
    const float* wq   = (const float*)d_in[12];
    const float* wk   = (const float*)d_in[13];
    const float* wv   = (const float*)d_in[14];
    const float* wqe  = (const float*)d_in[15];
    const float* wo   = (const float*)d_in[16];
    const float* bo   = (const float*)d_in[17];
    const float* lfg  = (const float*)d_in[18];
    const float* lfb  = (const float*)d_in[19];
    const float* w1   = (const float*)d_in[20];
    const float* b1   = (const float*)d_in[21];
    const float* w2   = (const float*)d_in[22];
    const float* b2   = (const float*)d_in[23];

    char* ws = (char*)d_ws;
    unsigned short* wp1  = (unsigned short*)(ws + WP1);
    unsigned short* wp2  = (unsigned short*)(ws + WP2);
    unsigned short* bpq  = (unsigned short*)(ws + BPQ);
    unsigned short* bpo  = (unsigned short*)(ws + BPO);
    unsigned short* bp1  = (unsigned short*)(ws + BP1);
    unsigned short* bp2  = (unsigned short*)(ws + BP2);
    unsigned short* xtp  = (unsigned short*)(ws + XTP);
    unsigned short* o1p  = (unsigned short*)(ws + O1P);
    float*          tb   = (float*)(ws + TBUF);
    unsigned short* qb   = (unsigned short*)(ws + QB);
    unsigned short* e0p  = (unsigned short*)(ws + E0P);
    float*          dist = (float*)(ws + DIST);
    float*          cdv  = (float*)(ws + CANDV);
    int*            cdi  = (int*)(ws + CANDI);
    float*          kb   = (float*)(ws + KBF);
    float*          vbuf = (float*)(ws + VBF);
    float*          outp = (float*)d_out;

    setup_k<<<944, 256, 0, stream>>>(x, c1w, c2w, wq, wo, w1, w2,
                                     wp1, wp2, bpq, bpo, bp1, bp2, xtp, o1p);
    conv_mfma<0><<<512, 256, 0, stream>>>(xtp, wp1, bn1g, bn1b, nullptr, o1p, nullptr);
    conv_mfma<1><<<512, 256, 0, stream>>>(o1p, wp2, bn2g, bn2b, xtp, nullptr, tb);
    lnq_k<<<128, 256, 0, stream>>>(tb, lag, labp, bpq, wqe, qb, e0p);
    lndist_k<<<3125, 256, 0, stream>>>(rdat, lcg, lcb, e0p, dist);
    topk1w<<<dim3(16, 32), 256, 0, stream>>>(dist, cdv, cdi);
    selkv_k<<<32, 256, 0, stream>>>(cdv, cdi, rdat, lcg, lcb, wk, wv, kb, vbuf);
    tail_k<<<256, 256, 0, stream>>>(qb, kb, vbuf, bpo, bo, tb, lfg, lfb, bp1, b1, bp2, b2, outp);
}

// Round 6
// 393.986 us; speedup vs baseline: 1.0175x; 1.0175x over previous
//
#include <hip/hip_runtime.h>
#include <hip/hip_bf16.h>
#include <math.h>

#define DEV __device__ __forceinline__

typedef __attribute__((ext_vector_type(8))) short bf16x8;   // 8 bf16 in 4 VGPRs
typedef __attribute__((ext_vector_type(4))) float f32x4;
typedef __attribute__((ext_vector_type(4))) unsigned int u32x4;
typedef __attribute__((ext_vector_type(2))) unsigned int u32x2;

DEV float b2f(unsigned int u) { return __uint_as_float(u << 16); }
DEV unsigned short f2b(float f) {            // round-to-nearest-even bf16
    unsigned int x = __float_as_uint(f);
    unsigned int r = x + 0x7fffu + ((x >> 16) & 1u);
    return (unsigned short)(r >> 16);
}
DEV unsigned int pack2(float a, float b) {
    return (unsigned int)f2b(a) | ((unsigned int)f2b(b) << 16);
}
DEV float gelu_exact(float g) {
    return 0.5f * g * (1.f + erff(g * 0.70710678118654752f));
}

// ---------------- workspace layout (bytes) ----------------
constexpr size_t WP1  = 0;                 // conv1 packed w
constexpr size_t WP2  = WP1  + 1179648;
constexpr size_t BPQ  = WP2  + 1179648;    // wq packed
constexpr size_t BPO  = BPQ  + 32768;      // wo packed
constexpr size_t BP1  = BPO  + 32768;      // w1 packed
constexpr size_t BP2  = BP1  + 262144;     // w2 packed
constexpr size_t XTP  = BP2  + 131072;     // x channel-last padded [32][324][256] bf16
constexpr size_t O1P  = XTP  + 5308416;    // conv1 out, padded layout, bf16
constexpr size_t TBUF = O1P  + 5308416;    // t [8192][256] f32
constexpr size_t QB   = TBUF + 8388608;    // q [8192][64] bf16
constexpr size_t E0P  = QB   + 1048576;    // e0 packed B-frags, 16 KB
constexpr size_t DIST = E0P  + 16384;      // [32][100000] f32
constexpr size_t CANDV= DIST + 12800000;   // [32][2048] f32
constexpr size_t CANDI= CANDV+ 262144;     // [32][2048] i32
constexpr size_t IDXB = CANDI+ 262144;     // (unused)
constexpr size_t KBF  = IDXB + 4096;       // k [32][32][64] f32
constexpr size_t VBF  = KBF  + 262144;     // v
constexpr size_t OBF  = VBF  + 262144;     // o [8192][64] bf16

// ================ setup: weight repacks + x transpose/pad (balanced) ================
// blocks: [0,576) conv-w repack, [576,688) gemm-w repack, [688,944) x transpose (img x 8 cc)
__global__ __launch_bounds__(256) void setup_k(
    const float* __restrict__ x, const float* __restrict__ c1w, const float* __restrict__ c2w,
    const float* __restrict__ wq, const float* __restrict__ wo,
    const float* __restrict__ w1, const float* __restrict__ w2,
    unsigned short* __restrict__ wp1, unsigned short* __restrict__ wp2,
    unsigned short* __restrict__ pq, unsigned short* __restrict__ po,
    unsigned short* __restrict__ p1, unsigned short* __restrict__ p2,
    unsigned short* __restrict__ xtp, unsigned short* __restrict__ o1p)
{
    int blk = blockIdx.x, tid = threadIdx.x;
    if (blk < 576) {
        const float* src = (blk < 288) ? c1w : c2w;
        unsigned short* dst = (blk < 288) ? wp1 : wp2;
        int f = (blk % 288) * 256 + tid;
        int lane = f & 63, s = f >> 6;
        int t = s >> 7, rem = s & 127, kc = rem >> 4, ntg = rem & 15;
        int co = ntg * 16 + (lane & 15);
        int ci0 = kc * 32 + ((lane >> 4) << 3);
        unsigned short v[8];
#pragma unroll
        for (int j = 0; j < 8; ++j) v[j] = f2b(src[((size_t)co * 256 + ci0 + j) * 9 + t]);
        u32x4 q;
        q.x = (unsigned)v[0] | ((unsigned)v[1] << 16);
        q.y = (unsigned)v[2] | ((unsigned)v[3] << 16);
        q.z = (unsigned)v[4] | ((unsigned)v[5] << 16);
        q.w = (unsigned)v[6] | ((unsigned)v[7] << 16);
        *(u32x4*)(dst + (size_t)f * 8) = q;
    } else if (blk < 688) {
        int f = (blk - 576) * 256 + tid;   // 0..28671
        const float* src; unsigned short* dst; int NTT, lf;
        if (f < 2048)       { src = wq; dst = pq; NTT = 4;  lf = f; }
        else if (f < 4096)  { src = wo; dst = po; NTT = 16; lf = f - 2048; }
        else if (f < 20480) { src = w1; dst = p1; NTT = 32; lf = f - 4096; }
        else                { src = w2; dst = p2; NTT = 16; lf = f - 20480; }
        int lane = lf & 63, s = lf >> 6;
        int kc = s / NTT, ntg = s % NTT;
        int N = NTT * 16;
        int k0 = kc * 32 + ((lane >> 4) << 3), n = ntg * 16 + (lane & 15);
        unsigned short v[8];
#pragma unroll
        for (int j = 0; j < 8; ++j) v[j] = f2b(src[(size_t)(k0 + j) * N + n]);
        u32x4 q;
        q.x = (unsigned)v[0] | ((unsigned)v[1] << 16);
        q.y = (unsigned)v[2] | ((unsigned)v[3] << 16);
        q.z = (unsigned)v[4] | ((unsigned)v[5] << 16);
        q.w = (unsigned)v[6] | ((unsigned)v[7] << 16);
        *(u32x4*)(dst + (size_t)lf * 8) = q;
    } else {
        int t = blk - 688;                 // 0..255 : img(32) x cc(8)
        int img = t >> 3, cc = t & 7;
        int h = tid >> 4, w = tid & 15;
        unsigned short* dst = xtp + ((size_t)img * 324 + (h + 1) * 18 + (w + 1)) * 256 + cc * 32;
        const float* src = x + (size_t)img * 65536 + (size_t)cc * 32 * 256 + tid;
        unsigned short v[32];
#pragma unroll
        for (int j = 0; j < 32; ++j) v[j] = f2b(src[j * 256]);
        u32x4* dp = (u32x4*)dst;
#pragma unroll
        for (int i = 0; i < 4; ++i) {
            u32x4 q;
            q.x = (unsigned)v[i*8+0] | ((unsigned)v[i*8+1] << 16);
            q.y = (unsigned)v[i*8+2] | ((unsigned)v[i*8+3] << 16);
            q.z = (unsigned)v[i*8+4] | ((unsigned)v[i*8+5] << 16);
            q.w = (unsigned)v[i*8+6] | ((unsigned)v[i*8+7] << 16);
            dp[i] = q;
        }
        // each cc-block zeroes its own 64B channel slice of the halo cells
        for (int cell = tid; cell < 324; cell += 256) {
            int hh = cell / 18, ww = cell - hh * 18;
            if (hh == 0 || hh == 17 || ww == 0 || ww == 17) {
                u32x4 z = (u32x4)0u;
                u32x4* zp1 = (u32x4*)(xtp + ((size_t)img * 324 + cell) * 256 + cc * 32);
                u32x4* zp2 = (u32x4*)(o1p + ((size_t)img * 324 + cell) * 256 + cc * 32);
#pragma unroll
                for (int i = 0; i < 4; ++i) { zp1[i] = z; zp2[i] = z; }
            }
        }
    }
}

// ================ conv: 9-tap implicit GEMM, 64x64 tile, K-split x4 (R2, verified) ================
template<int EPI>
__global__ __launch_bounds__(256, 2) void conv_mfma(const unsigned short* __restrict__ Asrc,
                                                    const unsigned short* __restrict__ wpack,
                                                    const float* __restrict__ bng,
                                                    const float* __restrict__ bnb,
                                                    const unsigned short* __restrict__ resid,
                                                    unsigned short* __restrict__ outP,
                                                    float* __restrict__ outT)
{
    __shared__ __align__(16) float part[4][4][4][64][4];   // [wave][mt][nt][lane][r] = 64 KB
    int blk = blockIdx.x;                   // 512 blocks
    int img = blk >> 4, rem = blk & 15;
    int mo = rem >> 2, nq = rem & 3;
    int tid = threadIdx.x;
    int wv = tid >> 6, lane = tid & 63;
    int lq = lane >> 4, lr = lane & 15;
    int m0 = mo * 64;
    int n0 = nq * 64;

    f32x4 acc[4][4];
#pragma unroll
    for (int i = 0; i < 4; ++i)
#pragma unroll
        for (int j = 0; j < 4; ++j) acc[i][j] = 0.f;

    int abase[4];
#pragma unroll
    for (int mt = 0; mt < 4; ++mt) {
        int m = m0 + mt * 16 + lr;
        int h = m >> 4, w = m & 15;
        abase[mt] = (img * 324 + (h + 1) * 18 + (w + 1)) * 256 + lq * 8;
    }
    int bb0 = (n0 >> 4) * 512 + lane * 8;

    for (int kc2 = 0; kc2 < 2; ++kc2) {
        int kc = wv * 2 + kc2;
#pragma unroll
        for (int tap = 0; tap < 9; ++tap) {
            int dh = tap / 3 - 1, dw = tap % 3 - 1;
            int aoff = (dh * 18 + dw) * 256 + kc * 32;
            bf16x8 a[4], b[4];
#pragma unroll
            for (int mt = 0; mt < 4; ++mt) a[mt] = *(const bf16x8*)(Asrc + abase[mt] + aoff);
            int boff = (tap * 8 + kc) * 8192 + bb0;
#pragma unroll
            for (int nt = 0; nt < 4; ++nt) b[nt] = *(const bf16x8*)(wpack + boff + nt * 512);
#pragma unroll
            for (int mt = 0; mt < 4; ++mt)
#pragma unroll
                for (int nt = 0; nt < 4; ++nt)
                    acc[mt][nt] = __builtin_amdgcn_mfma_f32_16x16x32_bf16(a[mt], b[nt], acc[mt][nt], 0, 0, 0);
        }
    }
    // publish partials
#pragma unroll
    for (int mt = 0; mt < 4; ++mt)
#pragma unroll
        for (int nt = 0; nt < 4; ++nt)
            *(f32x4*)&part[wv][mt][nt][lane][0] = acc[mt][nt];
    __syncthreads();
    // wave wv combines + epilogues quadrant mt = wv
    int mt = wv;
#pragma unroll
    for (int nt = 0; nt < 4; ++nt) {
        f32x4 s0 = *(const f32x4*)&part[0][mt][nt][lane][0];
        f32x4 s1 = *(const f32x4*)&part[1][mt][nt][lane][0];
        f32x4 s2 = *(const f32x4*)&part[2][mt][nt][lane][0];
        f32x4 s3 = *(const f32x4*)&part[3][mt][nt][lane][0];
        f32x4 sum;
#pragma unroll
        for (int r = 0; r < 4; ++r) sum[r] = (s0[r] + s1[r]) + (s2[r] + s3[r]);
        int co = n0 + nt * 16 + lr;
        float g = bng[co], bb = bnb[co];
#pragma unroll
        for (int r = 0; r < 4; ++r) {
            int m = m0 + mt * 16 + lq * 4 + r;
            int h = m >> 4, w = m & 15;
            float v = sum[r] * g + bb;
            if (EPI == 0) {
                v = fmaxf(v, 0.f);
                outP[((size_t)img * 324 + (h + 1) * 18 + (w + 1)) * 256 + co] = f2b(v);
            } else {
                v += b2f(resid[((size_t)img * 324 + (h + 1) * 18 + (w + 1)) * 256 + co]);
                v = fmaxf(v, 0.f);
                outT[((size_t)img * 256 + m) * 256 + co] = v;
            }
        }
    }
}

// ================ fused LN(t) + q-GEMM + e0 (R9, passed) ================
__global__ __launch_bounds__(256) void lnq_k(
    const float* __restrict__ t, const float* __restrict__ g, const float* __restrict__ bta,
    const unsigned short* __restrict__ bpq, const float* __restrict__ wqe,
    unsigned short* __restrict__ qb, unsigned short* __restrict__ e0p)
{
    __shared__ __align__(16) unsigned int frag[64 * 132];   // 33792 B
    __shared__ float qrow[64];
    int bx = blockIdx.x, tid = threadIdx.x;
    int wv = tid >> 6, lane = tid & 63;
    int c = lane * 4;
    f32x4 gv = *(const f32x4*)(g + c);
    f32x4 bv = *(const f32x4*)(bta + c);
#pragma unroll
    for (int p = 0; p < 16; ++p) {
        int rl = wv * 16 + p;
        f32x4 x = *(const f32x4*)(t + (size_t)(bx * 64 + rl) * 256 + c);
        float s  = x[0] + x[1] + x[2] + x[3];
        float ss = x[0]*x[0] + x[1]*x[1] + x[2]*x[2] + x[3]*x[3];
#pragma unroll
        for (int off = 32; off >= 1; off >>= 1) { s += __shfl_xor(s, off); ss += __shfl_xor(ss, off); }
        float mean = s * (1.f / 256.f);
        float var  = ss * (1.f / 256.f) - mean * mean;
        float rstd = rsqrtf(fmaxf(var, 0.f) + 1e-5f);
        float y0 = (x[0]-mean)*rstd*gv[0] + bv[0];
        float y1 = (x[1]-mean)*rstd*gv[1] + bv[1];
        float y2 = (x[2]-mean)*rstd*gv[2] + bv[2];
        float y3 = (x[3]-mean)*rstd*gv[3] + bv[3];
        frag[rl * 132 + 2 * lane]     = pack2(y0, y1);
        frag[rl * 132 + 2 * lane + 1] = pack2(y2, y3);
    }
    __syncthreads();
    int lq = lane >> 4, lr = lane & 15;
    f32x4 acc[4];
#pragma unroll
    for (int nt = 0; nt < 4; ++nt) acc[nt] = 0.f;
    const short* sA = (const short*)frag;
#pragma unroll
    for (int kc = 0; kc < 8; ++kc) {
        bf16x8 a = *(const bf16x8*)(sA + (wv * 16 + lr) * 264 + kc * 32 + lq * 8);
#pragma unroll
        for (int nt = 0; nt < 4; ++nt) {
            bf16x8 bfr = *(const bf16x8*)(bpq + (size_t)(kc * 4 + nt) * 512 + lane * 8);
            acc[nt] = __builtin_amdgcn_mfma_f32_16x16x32_bf16(a, bfr, acc[nt], 0, 0, 0);
        }
    }
#pragma unroll
    for (int nt = 0; nt < 4; ++nt)
#pragma unroll
        for (int r = 0; r < 4; ++r)
            qb[(size_t)(bx * 64 + wv * 16 + lq * 4 + r) * 64 + nt * 16 + lr] = f2b(acc[nt][r]);
    if ((bx & 3) == 0 && wv == 0 && lq == 0) {
#pragma unroll
        for (int nt = 0; nt < 4; ++nt) qrow[nt * 16 + lr] = acc[nt][0];
    }
    __syncthreads();
    if ((bx & 3) == 0) {
        int b = bx >> 2;
        int r = tid;
        float a2 = 0.f;
#pragma unroll 8
        for (int d = 0; d < 64; ++d) a2 += qrow[d] * wqe[d * 256 + r];
        int nt = b >> 4, kc = r >> 5;
        int ln_ = (b & 15) + (((r >> 3) & 3) << 4);
        int j = r & 7;
        e0p[(((nt * 8 + kc) * 64) + ln_) * 8 + j] = f2b(a2);
    }
}

// ================ fused ctx-LN + dist GEMM v4 (R8, verified) ================
__global__ __launch_bounds__(256, 4) void lndist_k(
    const float* __restrict__ ctx, const float* __restrict__ lgam, const float* __restrict__ lbet,
    const unsigned short* __restrict__ e0p, float* __restrict__ dist)
{
    __shared__ __align__(16) unsigned int frag[32 * 132];
    __shared__ __align__(16) float rn2s[32];
    int r0 = blockIdx.x * 32;
    int tid = threadIdx.x;
    int wv = tid >> 6, lane = tid & 63;

    float2 d0[8], d1[8], d2[8];
    const float* base = ctx + (size_t)(r0 + wv * 8) * 266;
#pragma unroll
    for (int p = 0; p < 8; ++p) {
        const float* rowp = base + p * 266;
        d0[p] = *(const float2*)(rowp + 2 * lane);
        d1[p] = *(const float2*)(rowp + 128 + 2 * lane);
        if (lane < 5) d2[p] = *(const float2*)(rowp + 256 + 2 * lane);
        else { d2[p].x = 0.f; d2[p].y = 0.f; }
    }
    float2 g0 = *(const float2*)(lgam + 2 * lane);
    float2 g1 = *(const float2*)(lgam + 128 + 2 * lane);
    float2 b0 = *(const float2*)(lbet + 2 * lane);
    float2 b1 = *(const float2*)(lbet + 128 + 2 * lane);

#pragma unroll
    for (int p = 0; p < 8; ++p) {
        int rl = wv * 8 + p;
        float s  = d0[p].x + d0[p].y + d1[p].x + d1[p].y + d2[p].x + d2[p].y;
        float ss = d0[p].x*d0[p].x + d0[p].y*d0[p].y + d1[p].x*d1[p].x + d1[p].y*d1[p].y
                 + d2[p].x*d2[p].x + d2[p].y*d2[p].y;
#pragma unroll
        for (int off = 32; off >= 1; off >>= 1) { s += __shfl_xor(s, off); ss += __shfl_xor(ss, off); }
        float mean = s * (1.f / 266.f);
        float var  = ss * (1.f / 266.f) - mean * mean;
        float rstd = rsqrtf(fmaxf(var, 0.f) + 1e-5f);
        float c0 = (d0[p].x - mean) * rstd * g0.x + b0.x;
        float c1 = (d0[p].y - mean) * rstd * g0.y + b0.y;
        float c2 = (d1[p].x - mean) * rstd * g1.x + b1.x;
        float c3 = (d1[p].y - mean) * rstd * g1.y + b1.y;
        frag[rl * 132 + lane]      = pack2(c0, c1);
        frag[rl * 132 + 64 + lane] = pack2(c2, c3);
        float nsq = c0*c0 + c1*c1 + c2*c2 + c3*c3;
#pragma unroll
        for (int off = 32; off >= 1; off >>= 1) nsq += __shfl_xor(nsq, off);
        if (lane == 0) rn2s[rl] = nsq;
    }
    __syncthreads();

    int lq = lane >> 4, lr = lane & 15;
    int rt = wv & 1, ch = wv >> 1;
    f32x4 acc = 0.f;
    const short* sA = (const short*)frag;
#pragma unroll
    for (int kc = 0; kc < 8; ++kc) {
        bf16x8 a = *(const bf16x8*)(sA + (rt * 16 + lr) * 264 + kc * 32 + lq * 8);
        bf16x8 b = *(const bf16x8*)(e0p + ((ch * 8 + kc) * 64 + lane) * 8);
        acc = __builtin_amdgcn_mfma_f32_16x16x32_bf16(a, b, acc, 0, 0, 0);
    }
    int mbase = r0 + rt * 16 + lq * 4;
    f32x4 rv = *(f32x4*)(rn2s + rt * 16 + lq * 4);
    f32x4 o;
#pragma unroll
    for (int r = 0; r < 4; ++r) o[r] = rv[r] - 2.f * acc[r];
    *(f32x4*)(dist + (size_t)(ch * 16 + lr) * 100000 + mbase) = o;
}

// ================ top-32 stage 1: wave-synchronous, 4 independent quarter-chunks ================
// grid (16,32): block = (chunk c, batch b). Wave w selects top-32 of sv[w*1600 .. +1600)
// (chunk 6250 padded to 6400 with +INF). No block barriers, no serial tail.
// Output: candv/candi[b][c*4+w][32]  -> 2048 candidates per batch.
__global__ __launch_bounds__(256) void topk1w(const float* __restrict__ dist,
                                              float* __restrict__ candv,
                                              int* __restrict__ candi)
{
    __shared__ float sv[6400];
    int c = blockIdx.x, b = blockIdx.y;
    int tid = threadIdx.x;
    int wv = tid >> 6, lane = tid & 63;
    const float* src = dist + (size_t)b * 100000 + c * 6250;
    for (int i = tid; i < 6250; i += 256) sv[i] = src[i];
    for (int i = 6250 + tid; i < 6400; i += 256) sv[i] = 3e38f;
    __syncthreads();
    int base = wv * 1600;
    float* cvp = candv + (((size_t)b * 16 + c) * 4 + wv) * 32;
    int*   cip = candi + (((size_t)b * 16 + c) * 4 + wv) * 32;
    for (int it = 0; it < 32; ++it) {
        float lm = 3e38f; int li = base;
#pragma unroll
        for (int t = 0; t < 25; ++t) {
            int i = base + lane + t * 64;
            float v = sv[i];
            if (v < lm) { lm = v; li = i; }
        }
#pragma unroll
        for (int off = 32; off >= 1; off >>= 1) {
            float ov = __shfl_xor(lm, off);
            int oi = __shfl_xor(li, off);
            if (ov < lm) { lm = ov; li = oi; }
        }
        if (lane == 0) {
            cvp[it] = lm;
            cip[it] = c * 6250 + li;
            sv[li] = 3e38f;
        }
        __builtin_amdgcn_wave_barrier();
    }
}

// ================ selection stage 2 + gather + LN + k/v projections (fused) ================
// 32 blocks (one per batch). Phase 1: hierarchical exact top-32 of 2048 candidates
// (wave-sync 512->32 per wave, then wave0 merges 128->32, order = ascending dist).
// Phase 2: gather rows, LN into LDS. Phase 3: k/v matvec with wk-load reuse.
__global__ __launch_bounds__(256) void selkv_k(const float* __restrict__ candv,
                                               const int* __restrict__ candi,
                                               const float* __restrict__ ctx,
                                               const float* __restrict__ g,
                                               const float* __restrict__ bta,
                                               const float* __restrict__ wk,
                                               const float* __restrict__ wvm,
                                               float* __restrict__ kb,
                                               float* __restrict__ vb)
{
    __shared__ float sv[2048]; __shared__ int si[2048];
    __shared__ float fv[128];  __shared__ int fi[128];
    __shared__ int rows[32];
    __shared__ float cnv[32][268];
    int b = blockIdx.x, tid = threadIdx.x;
    int wv = tid >> 6, lane = tid & 63;
    for (int i = tid; i < 2048; i += 256) {
        sv[i] = candv[(size_t)b * 2048 + i];
        si[i] = candi[(size_t)b * 2048 + i];
    }
    __syncthreads();
    // wave-level: top-32 of each 512-candidate strip
    {
        int base = wv * 512;
        for (int it = 0; it < 32; ++it) {
            float lm = 3e38f; int li = base;
#pragma unroll
            for (int t = 0; t < 8; ++t) {
                int i = base + lane + t * 64;
                float v = sv[i];
                if (v < lm) { lm = v; li = i; }
            }
#pragma unroll
            for (int off = 32; off >= 1; off >>= 1) {
                float ov = __shfl_xor(lm, off);
                int oi = __shfl_xor(li, off);
                if (ov < lm) { lm = ov; li = oi; }
            }
            if (lane == 0) { fv[wv * 32 + it] = lm; fi[wv * 32 + it] = si[li]; sv[li] = 3e38f; }
            __builtin_amdgcn_wave_barrier();
        }
    }
    __syncthreads();
    // wave 0 merges 128 -> 32 (ascending)
    if (wv == 0) {
        for (int it = 0; it < 32; ++it) {
            float lm = 3e38f; int li = 0;
#pragma unroll
            for (int t = 0; t < 2; ++t) {
                int i = lane + t * 64;
                float v = fv[i];
                if (v < lm) { lm = v; li = i; }
            }
#pragma unroll
            for (int off = 32; off >= 1; off >>= 1) {
                float ov = __shfl_xor(lm, off);
                int oi = __shfl_xor(li, off);
                if (ov < lm) { lm = ov; li = oi; }
            }
            if (lane == 0) { rows[it] = fi[li]; fv[li] = 3e38f; }
            __builtin_amdgcn_wave_barrier();
        }
    }
    __syncthreads();
    // gather + LN: wave w handles rows j = w*8 .. w*8+7
    for (int p = 0; p < 8; ++p) {
        int j = wv * 8 + p;
        int rrow = rows[j];
        const float* pp = ctx + (size_t)rrow * 266;
        float2 a0 = *(const float2*)(pp + 2 * lane);
        float2 a1 = *(const float2*)(pp + 128 + 2 * lane);
        float x4 = 0.f, x5 = 0.f;
        if (lane < 5) { float2 a2 = *(const float2*)(pp + 256 + 2 * lane); x4 = a2.x; x5 = a2.y; }
        float s  = a0.x + a0.y + a1.x + a1.y + x4 + x5;
        float ss = a0.x*a0.x + a0.y*a0.y + a1.x*a1.x + a1.y*a1.y + x4*x4 + x5*x5;
#pragma unroll
        for (int off = 32; off >= 1; off >>= 1) { s += __shfl_xor(s, off); ss += __shfl_xor(ss, off); }
        float mean = s * (1.f / 266.f);
        float var  = ss * (1.f / 266.f) - mean * mean;
        float rstd = rsqrtf(fmaxf(var, 0.f) + 1e-5f);
        float2 g0 = *(const float2*)(g + 2 * lane);
        float2 g1 = *(const float2*)(g + 128 + 2 * lane);
        float2 b0 = *(const float2*)(bta + 2 * lane);
        float2 b1 = *(const float2*)(bta + 128 + 2 * lane);
        cnv[j][2*lane]       = (a0.x - mean) * rstd * g0.x + b0.x;
        cnv[j][2*lane + 1]   = (a0.y - mean) * rstd * g0.y + b0.y;
        cnv[j][128 + 2*lane] = (a1.x - mean) * rstd * g1.x + b1.x;
        cnv[j][129 + 2*lane] = (a1.y - mean) * rstd * g1.y + b1.y;
        if (lane < 5) {
            float2 g2 = *(const float2*)(g + 256 + 2 * lane);
            float2 b2 = *(const float2*)(bta + 256 + 2 * lane);
            cnv[j][256 + 2*lane] = (x4 - mean) * rstd * g2.x + b2.x;
            cnv[j][257 + 2*lane] = (x5 - mean) * rstd * g2.y + b2.y;
        }
    }
    __syncthreads();
    // k projection: wave w computes rows j = w*8..w*8+7, col = lane; reuse wk loads across 8 rows
    {
        float acc[8];
#pragma unroll
        for (int p = 0; p < 8; ++p) acc[p] = 0.f;
        int j0 = wv * 8;
        for (int r = 0; r < 256; r += 4) {
            float w0 = wk[(r + 0) * 64 + lane];
            float w1_ = wk[(r + 1) * 64 + lane];
            float w2_ = wk[(r + 2) * 64 + lane];
            float w3 = wk[(r + 3) * 64 + lane];
#pragma unroll
            for (int p = 0; p < 8; ++p) {
                f32x4 cv = *(const f32x4*)&cnv[j0 + p][r];
                acc[p] += cv[0] * w0 + cv[1] * w1_ + cv[2] * w2_ + cv[3] * w3;
            }
        }
#pragma unroll
        for (int p = 0; p < 8; ++p)
            kb[((size_t)b * 32 + j0 + p) * 64 + lane] = acc[p];
        // v projection (10-dim)
#pragma unroll
        for (int p = 0; p < 8; ++p) {
            float a2 = 0.f;
#pragma unroll
            for (int r = 0; r < 10; ++r) a2 += cnv[j0 + p][256 + r] * wvm[r * 64 + lane];
            vb[((size_t)b * 32 + j0 + p) * 64 + lane] = a2;
        }
    }
}

// ================ attention v2 (R6, verified): wave = 2 px, 32 lanes/px ================
__global__ __launch_bounds__(256) void attn_k(const unsigned short* __restrict__ q,
                                              const float* __restrict__ kb,
                                              const float* __restrict__ vb,
                                              unsigned short* __restrict__ ob)
{
    __shared__ float kl[32 * 66];
    __shared__ float vl[32 * 66];
    __shared__ float ql[8 * 64];
    __shared__ float pl[8 * 32];
    int b = blockIdx.x >> 5, pxg = blockIdx.x & 31;
    int px_base = pxg * 8;
    int tid = threadIdx.x;

    for (int i = tid; i < 2048; i += 256) {
        int row = i >> 6, d = i & 63;
        kl[row * 66 + d] = kb[(size_t)b * 2048 + i];
        vl[row * 66 + d] = vb[(size_t)b * 2048 + i];
    }
    for (int i = tid; i < 512; i += 256) {
        ql[i] = b2f(q[((size_t)b * 256 + px_base) * 64 + i]);
    }
    __syncthreads();

    int wv = tid >> 6, lane = tid & 63;
    int lp = wv * 2 + (lane >> 5);
    int j = lane & 31;

    const float* qp = ql + lp * 64;
    const float* kp = kl + j * 66;
    float s = 0.f;
#pragma unroll
    for (int d = 0; d < 64; ++d) s += qp[d] * kp[d];
    s *= 0.125f;

    float mx = s;
#pragma unroll
    for (int off = 16; off >= 1; off >>= 1) mx = fmaxf(mx, __shfl_xor(mx, off));
    float p = expf(s - mx);
    float sum = p;
#pragma unroll
    for (int off = 16; off >= 1; off >>= 1) sum += __shfl_xor(sum, off);
    p /= sum;
    pl[lp * 32 + j] = p;

    int d0 = 2 * j;
    float o0 = 0.f, o1 = 0.f;
#pragma unroll
    for (int jj = 0; jj < 32; ++jj) {
        float pj = pl[lp * 32 + jj];
        float2 vv = *(const float2*)(vl + jj * 66 + d0);
        o0 += pj * vv.x;
        o1 += pj * vv.y;
    }
    ((unsigned int*)ob)[(((size_t)b * 256 + px_base + lp) * 64 + d0) >> 1] = pack2(o0, o1);
}

// ================ tail: wo GEMM + LN + ff1/GeGLU + ff2 + residuals + transposed store ================
// 256 blocks x 32 rows. t2 and xn2/u never leave LDS.
__global__ __launch_bounds__(256) void tail_k(
    const unsigned short* __restrict__ A,    // ob [8192][64] bf16
    const unsigned short* __restrict__ Bpo,  // wo packed (NTT=16)
    const float* __restrict__ bo, const float* __restrict__ tres,
    const float* __restrict__ lng, const float* __restrict__ lnb,
    const unsigned short* __restrict__ Bp1, const float* __restrict__ b1, // w1 packed (NTT=32)
    const unsigned short* __restrict__ Bp2, const float* __restrict__ b2, // w2 packed (NTT=16)
    float* __restrict__ out)
{
    __shared__ __align__(16) float tile[32 * 268];          // wo acc -> t2 -> ff2 result
    __shared__ __align__(16) unsigned short xt[32 * 264];   // LN out (bf16) -> u (bf16)
    int m0 = blockIdx.x * 32;
    int tid = threadIdx.x, wv = tid >> 6, lane = tid & 63, lq = lane >> 4, lr = lane & 15;
    int n0 = wv * 64;
    const short* xts = (const short*)xt;

    // ---- phase A: wo GEMM (K=64), wave w -> cols n0..n0+64 ----
    {
        f32x4 acc[2][4];
#pragma unroll
        for (int i = 0; i < 2; ++i)
#pragma unroll
            for (int j = 0; j < 4; ++j) acc[i][j] = 0.f;
        const unsigned short* a0p = A + (size_t)(m0 + lr) * 64 + lq * 8;
#pragma unroll
        for (int kc = 0; kc < 2; ++kc) {
            bf16x8 a0 = *(const bf16x8*)(a0p + kc * 32);
            bf16x8 a1 = *(const bf16x8*)(a0p + 16 * 64 + kc * 32);
#pragma unroll
            for (int nt = 0; nt < 4; ++nt) {
                bf16x8 bfr = *(const bf16x8*)(Bpo + (size_t)(kc * 16 + (n0 >> 4) + nt) * 512 + lane * 8);
                acc[0][nt] = __builtin_amdgcn_mfma_f32_16x16x32_bf16(a0, bfr, acc[0][nt], 0, 0, 0);
                acc[1][nt] = __builtin_amdgcn_mfma_f32_16x16x32_bf16(a1, bfr, acc[1][nt], 0, 0, 0);
            }
        }
#pragma unroll
        for (int mt = 0; mt < 2; ++mt)
#pragma unroll
            for (int nt = 0; nt < 4; ++nt)
#pragma unroll
                for (int r = 0; r < 4; ++r)
                    tile[(mt * 16 + lq * 4 + r) * 268 + n0 + nt * 16 + lr] = acc[mt][nt][r];
    }
    __syncthreads();

    // ---- phase B: + bias + residual -> t2 (back into tile); LN -> xt (bf16) ----
    {
        int row = tid >> 3, c0 = (tid & 7) * 32;
        const float* trp = tres + (size_t)(m0 + row) * 256 + c0;
        float v[32];
#pragma unroll
        for (int i = 0; i < 8; ++i) {
            f32x4 t4 = *(f32x4*)(tile + row * 268 + c0 + i * 4);
            f32x4 rr = *(const f32x4*)(trp + i * 4);
            f32x4 bb = *(const f32x4*)(bo + c0 + i * 4);
#pragma unroll
            for (int k = 0; k < 4; ++k) v[i*4+k] = t4[k] + rr[k] + bb[k];
        }
#pragma unroll
        for (int i = 0; i < 8; ++i) {
            f32x4 o; o[0] = v[i*4]; o[1] = v[i*4+1]; o[2] = v[i*4+2]; o[3] = v[i*4+3];
            *(f32x4*)(tile + row * 268 + c0 + i * 4) = o;   // t2
        }
        float s = 0.f, ss = 0.f;
#pragma unroll
        for (int i = 0; i < 32; ++i) { s += v[i]; ss += v[i] * v[i]; }
#pragma unroll
        for (int off = 1; off <= 4; off <<= 1) { s += __shfl_xor(s, off); ss += __shfl_xor(ss, off); }
        float mean = s * (1.f / 256.f);
        float var  = ss * (1.f / 256.f) - mean * mean;
        float rstd = rsqrtf(fmaxf(var, 0.f) + 1e-5f);
        unsigned int pk[16];
#pragma unroll
        for (int i = 0; i < 16; ++i) {
            float y0 = (v[2*i]   - mean) * rstd * lng[c0+2*i]   + lnb[c0+2*i];
            float y1 = (v[2*i+1] - mean) * rstd * lng[c0+2*i+1] + lnb[c0+2*i+1];
            pk[i] = pack2(y0, y1);
        }
        u32x4* dp = (u32x4*)(xt + row * 264 + c0);
#pragma unroll
        for (int i = 0; i < 4; ++i) {
            u32x4 o; o.x = pk[i*4]; o.y = pk[i*4+1]; o.z = pk[i*4+2]; o.w = pk[i*4+3];
            dp[i] = o;
        }
    }
    __syncthreads();

    // ---- phase C: ff1 (K=256). wave w -> a-cols [n0,n0+64), g-cols [256+n0, ...) ----
    f32x4 fa[2][4], fg[2][4];
#pragma unroll
    for (int i = 0; i < 2; ++i)
#pragma unroll
        for (int j = 0; j < 4; ++j) { fa[i][j] = 0.f; fg[i][j] = 0.f; }
#pragma unroll
    for (int kc = 0; kc < 8; ++kc) {
        bf16x8 a0 = *(const bf16x8*)(xts + lr * 264 + kc * 32 + lq * 8);
        bf16x8 a1 = *(const bf16x8*)(xts + (16 + lr) * 264 + kc * 32 + lq * 8);
#pragma unroll
        for (int nt = 0; nt < 4; ++nt) {
            bf16x8 bA = *(const bf16x8*)(Bp1 + (size_t)(kc * 32 + (n0 >> 4) + nt) * 512 + lane * 8);
            bf16x8 bG = *(const bf16x8*)(Bp1 + (size_t)(kc * 32 + 16 + (n0 >> 4) + nt) * 512 + lane * 8);
            fa[0][nt] = __builtin_amdgcn_mfma_f32_16x16x32_bf16(a0, bA, fa[0][nt], 0, 0, 0);
            fa[1][nt] = __builtin_amdgcn_mfma_f32_16x16x32_bf16(a1, bA, fa[1][nt], 0, 0, 0);
            fg[0][nt] = __builtin_amdgcn_mfma_f32_16x16x32_bf16(a0, bG, fg[0][nt], 0, 0, 0);
            fg[1][nt] = __builtin_amdgcn_mfma_f32_16x16x32_bf16(a1, bG, fg[1][nt], 0, 0, 0);
        }
    }
    __syncthreads();   // all xt reads done
    // GeGLU -> u into xt
#pragma unroll
    for (int nt = 0; nt < 4; ++nt) {
        int col = n0 + nt * 16 + lr;
        float ba = b1[col], bg = b1[256 + col];
#pragma unroll
        for (int mt = 0; mt < 2; ++mt)
#pragma unroll
            for (int r = 0; r < 4; ++r) {
                float a = fa[mt][nt][r] + ba;
                float gg = fg[mt][nt][r] + bg;
                xt[(mt * 16 + lq * 4 + r) * 264 + col] = f2b(a * gelu_exact(gg));
            }
    }
    __syncthreads();

    // ---- phase D: ff2 (K=256). wave w -> cols n0..n0+64; += b2 + t2; in-place into tile ----
    {
        f32x4 c2[2][4];
#pragma unroll
        for (int i = 0; i < 2; ++i)
#pragma unroll
            for (int j = 0; j < 4; ++j) c2[i][j] = 0.f;
#pragma unroll
        for (int kc = 0; kc < 8; ++kc) {
            bf16x8 a0 = *(const bf16x8*)(xts + lr * 264 + kc * 32 + lq * 8);
            bf16x8 a1 = *(const bf16x8*)(xts + (16 + lr) * 264 + kc * 32 + lq * 8);
#pragma unroll
            for (int nt = 0; nt < 4; ++nt) {
                bf16x8 bfr = *(const bf16x8*)(Bp2 + (size_t)(kc * 16 + (n0 >> 4) + nt) * 512 + lane * 8);
                c2[0][nt] = __builtin_amdgcn_mfma_f32_16x16x32_bf16(a0, bfr, c2[0][nt], 0, 0, 0);
                c2[1][nt] = __builtin_amdgcn_mfma_f32_16x16x32_bf16(a1, bfr, c2[1][nt], 0, 0, 0);
            }
        }
#pragma unroll
        for (int nt = 0; nt < 4; ++nt) {
            int col = n0 + nt * 16 + lr;
            float bv = b2[col];
#pragma unroll
            for (int mt = 0; mt < 2; ++mt)
#pragma unroll
                for (int r = 0; r < 4; ++r) {
                    int m = mt * 16 + lq * 4 + r;
                    tile[m * 268 + col] = c2[mt][nt][r] + bv + tile[m * 268 + col];
                }
        }
    }
    __syncthreads();

    // ---- transposed store: out[b][c][px0..px0+32) ----
    {
        int b = m0 >> 8, px0 = m0 & 255;
        int c = tid;
        float* dp = out + ((size_t)b * 256 + c) * 256 + px0;
#pragma unroll
        for (int q = 0; q < 8; ++q) {
            f32x4 o;
            o[0] = tile[(q * 4 + 0) * 268 + c];
            o[1] = tile[(q * 4 + 1) * 268 + c];
            o[2] = tile[(q * 4 + 2) * 268 + c];
            o[3] = tile[(q * 4 + 3) * 268 + c];
            *(f32x4*)(dp + q * 4) = o;
        }
    }
}

// ================ launch ================
extern "C" void kernel_launch(void* const* d_in, const int* in_sizes, int n_in,
                              void* d_out, int out_size, void* d_ws, size_t ws_size,
                              hipStream_t stream)
{
    (void)in_sizes; (void)n_in; (void)out_size; (void)ws_size;
    const float* x    = (const float*)d_in[0];
    const float* c1w  = (const float*)d_in[1];
    const float* c2w  = (const float*)d_in[2];
    const float* bn1g = (const float*)d_in[3];
    const float* bn1b = (const float*)d_in[4];
    const float* bn2g = (const float*)d_in[5];
    const float* bn2b = (const float*)d_in[6];
    const float* rdat = (const float*)d_in[7];
    const float* lag  = (const float*)d_in[8];
    const float* labp = (const float*)d_in[9];
    const float* lcg  = (const float*)d_in[10];
    const float* lcb  = (const float*)d_in[11];
    const float* wq   = (const float*)d_in[12];
    const float* wk   = (const float*)d_in[13];
    const float* wv   = (const float*)d_in[14];
    const float* wqe  = (const float*)d_in[15];
    const float* wo   = (const float*)d_in[16];
    const float* bo   = (const float*)d_in[17];
    const float* lfg  = (const float*)d_in[18];
    const float* lfb  = (const float*)d_in[19];
    const float* w1   = (const float*)d_in[20];
    const float* b1   = (const float*)d_in[21];
    const float* w2   = (const float*)d_in[22];
    const float* b2   = (const float*)d_in[23];

    char* ws = (char*)d_ws;
    unsigned short* wp1  = (unsigned short*)(ws + WP1);
    unsigned short* wp2  = (unsigned short*)(ws + WP2);
    unsigned short* bpq  = (unsigned short*)(ws + BPQ);
    unsigned short* bpo  = (unsigned short*)(ws + BPO);
    unsigned short* bp1  = (unsigned short*)(ws + BP1);
    unsigned short* bp2  = (unsigned short*)(ws + BP2);
    unsigned short* xtp  = (unsigned short*)(ws + XTP);
    unsigned short* o1p  = (unsigned short*)(ws + O1P);
    float*          tb   = (float*)(ws + TBUF);
    unsigned short* qb   = (unsigned short*)(ws + QB);
    unsigned short* e0p  = (unsigned short*)(ws + E0P);
    float*          dist = (float*)(ws + DIST);
    float*          cdv  = (float*)(ws + CANDV);
    int*            cdi  = (int*)(ws + CANDI);
    float*          kb   = (float*)(ws + KBF);
    float*          vbuf = (float*)(ws + VBF);
    unsigned short* ob   = (unsigned short*)(ws + OBF);
    float*          outp = (float*)d_out;

    setup_k<<<944, 256, 0, stream>>>(x, c1w, c2w, wq, wo, w1, w2,
                                     wp1, wp2, bpq, bpo, bp1, bp2, xtp, o1p);
    conv_mfma<0><<<512, 256, 0, stream>>>(xtp, wp1, bn1g, bn1b, nullptr, o1p, nullptr);
    conv_mfma<1><<<512, 256, 0, stream>>>(o1p, wp2, bn2g, bn2b, xtp, nullptr, tb);
    lnq_k<<<128, 256, 0, stream>>>(tb, lag, labp, bpq, wqe, qb, e0p);
    lndist_k<<<3125, 256, 0, stream>>>(rdat, lcg, lcb, e0p, dist);
    topk1w<<<dim3(16, 32), 256, 0, stream>>>(dist, cdv, cdi);
    selkv_k<<<32, 256, 0, stream>>>(cdv, cdi, rdat, lcg, lcb, wk, wv, kb, vbuf);
    attn_k<<<1024, 256, 0, stream>>>(qb, kb, vbuf, ob);
    tail_k<<<256, 256, 0, stream>>>(ob, bpo, bo, tb, lfg, lfb, bp1, b1, bp2, b2, outp);
}